// Round 1
// baseline (2763.932 us; speedup 1.0000x reference)
//
#include <hip/hip_runtime.h>

// COO SpMM: out[row[e], :] += values[e] * b[col[e], :]
// N=100000, E=1600000, D=128, fp32.
// v1: atomic scatter. 32 threads per edge, one float4 lane-chunk each.

#define D_DIM 128

__global__ void spmm_atomic_kernel(const int* __restrict__ rows,
                                   const int* __restrict__ cols,
                                   const float* __restrict__ vals,
                                   const float* __restrict__ b,
                                   float* __restrict__ out,
                                   int E) {
    int t = blockIdx.x * blockDim.x + threadIdx.x;
    int e = t >> 5;           // 32 threads per edge
    if (e >= E) return;
    int lane = t & 31;        // which float4 of the 128-wide row

    int r = rows[e];
    int c = cols[e];
    float v = vals[e];

    float4 bv = ((const float4*)(b + (size_t)c * D_DIM))[lane];

    float* op = out + (size_t)r * D_DIM + (size_t)lane * 4;
    atomicAdd(op + 0, v * bv.x);
    atomicAdd(op + 1, v * bv.y);
    atomicAdd(op + 2, v * bv.z);
    atomicAdd(op + 3, v * bv.w);
}

extern "C" void kernel_launch(void* const* d_in, const int* in_sizes, int n_in,
                              void* d_out, int out_size, void* d_ws, size_t ws_size,
                              hipStream_t stream) {
    const int*   indices = (const int*)d_in[0];
    const float* vals    = (const float*)d_in[1];
    // d_in[2] is the scalar n (unused on device; N = out_size / 128)
    const float* b       = (const float*)d_in[3];
    float*       out     = (float*)d_out;

    int E = in_sizes[1];                 // 1600000
    const int* rows = indices;           // indices[0, :]
    const int* cols = indices + E;       // indices[1, :]

    // d_out is re-poisoned to 0xAA before every timed launch — zero it.
    hipMemsetAsync(d_out, 0, (size_t)out_size * sizeof(float), stream);

    const int threads = 256;             // 8 edges per block
    long long total = (long long)E * 32;
    int blocks = (int)((total + threads - 1) / threads);
    spmm_atomic_kernel<<<blocks, threads, 0, stream>>>(rows, cols, vals, b, out, E);
}

// Round 2
// 395.221 us; speedup vs baseline: 6.9934x; 6.9934x over previous
//
#include <hip/hip_runtime.h>

// COO SpMM: out[row[e], :] += values[e] * b[col[e], :]
// N=100000, E=1600000, D=128, fp32.
// v2: device-built CSR (histogram -> scan -> scatter), then atomic-free
//     gather-accumulate: 32 lanes per row, float4 per lane, write-once output.

#define D_DIM 128

// ---------------- CSR build ----------------

__global__ void hist_kernel(const int* __restrict__ rows, int* __restrict__ counts, int E) {
    int e = blockIdx.x * blockDim.x + threadIdx.x;
    if (e < E) atomicAdd(&counts[rows[e]], 1);
}

// Block-level exclusive scan: 256 threads x 4 items = 1024 elements/block.
__global__ void scan_block_kernel(const int* __restrict__ counts,
                                  int* __restrict__ offsets,
                                  int* __restrict__ blocksums, int N) {
    __shared__ int sdata[256];
    int tid = threadIdx.x;
    int base = blockIdx.x * 1024 + tid * 4;
    int v[4];
    int local = 0;
#pragma unroll
    for (int j = 0; j < 4; ++j) {
        int idx = base + j;
        v[j] = (idx < N) ? counts[idx] : 0;
        local += v[j];
    }
    sdata[tid] = local;
    __syncthreads();
    // Hillis-Steele inclusive scan over thread sums
    for (int off = 1; off < 256; off <<= 1) {
        int t = (tid >= off) ? sdata[tid - off] : 0;
        __syncthreads();
        sdata[tid] += t;
        __syncthreads();
    }
    if (tid == 255) blocksums[blockIdx.x] = sdata[255];
    int run = sdata[tid] - local;  // exclusive prefix of this thread's chunk
#pragma unroll
    for (int j = 0; j < 4; ++j) {
        int idx = base + j;
        if (idx < N) offsets[idx] = run;
        run += v[j];
    }
}

// Single-block exclusive scan of block sums (nb <= 256).
__global__ void scan_sums_kernel(int* __restrict__ blocksums, int nb) {
    __shared__ int sdata[256];
    int tid = threadIdx.x;
    int v = (tid < nb) ? blocksums[tid] : 0;
    sdata[tid] = v;
    __syncthreads();
    for (int off = 1; off < 256; off <<= 1) {
        int t = (tid >= off) ? sdata[tid - off] : 0;
        __syncthreads();
        sdata[tid] += t;
        __syncthreads();
    }
    if (tid < nb) blocksums[tid] = sdata[tid] - v;
}

__global__ void add_base_kernel(int* __restrict__ offsets,
                                const int* __restrict__ blocksums,
                                int* __restrict__ cursor, int N) {
    int i = blockIdx.x * blockDim.x + threadIdx.x;
    if (i < N) {
        int o = offsets[i] + blocksums[i >> 10];
        offsets[i] = o;
        cursor[i] = o;
    }
}

__global__ void scatter_kernel(const int* __restrict__ rows,
                               const int* __restrict__ cols,
                               const float* __restrict__ vals,
                               int* __restrict__ cursor,
                               int* __restrict__ csr_col,
                               float* __restrict__ csr_val, int E) {
    int e = blockIdx.x * blockDim.x + threadIdx.x;
    if (e < E) {
        int r = rows[e];
        int pos = atomicAdd(&cursor[r], 1);
        csr_col[pos] = cols[e];
        csr_val[pos] = vals[e];
    }
}

// ---------------- gather-accumulate ----------------
// 32 lanes per row, each lane owns one float4 of the 128-wide row.
__global__ __launch_bounds__(256) void gather_kernel(
        const int* __restrict__ offsets,
        const int* __restrict__ counts,
        const int* __restrict__ csr_col,
        const float* __restrict__ csr_val,
        const float* __restrict__ b,
        float* __restrict__ out, int N) {
    int t = blockIdx.x * blockDim.x + threadIdx.x;
    int r = t >> 5;
    if (r >= N) return;
    int lane = t & 31;

    int off = offsets[r];
    int end = off + counts[r];

    float4 acc = make_float4(0.f, 0.f, 0.f, 0.f);
    for (int i = off; i < end; ++i) {
        int c = csr_col[i];
        float v = csr_val[i];
        float4 bv = ((const float4*)(b + (size_t)c * D_DIM))[lane];
        acc.x += v * bv.x;
        acc.y += v * bv.y;
        acc.z += v * bv.z;
        acc.w += v * bv.w;
    }
    ((float4*)(out + (size_t)r * D_DIM))[lane] = acc;
}

// ---------------- fallback (v1 atomic) ----------------
__global__ void spmm_atomic_kernel(const int* __restrict__ rows,
                                   const int* __restrict__ cols,
                                   const float* __restrict__ vals,
                                   const float* __restrict__ b,
                                   float* __restrict__ out, int E) {
    int t = blockIdx.x * blockDim.x + threadIdx.x;
    int e = t >> 5;
    if (e >= E) return;
    int lane = t & 31;
    int r = rows[e];
    int c = cols[e];
    float v = vals[e];
    float4 bv = ((const float4*)(b + (size_t)c * D_DIM))[lane];
    float* op = out + (size_t)r * D_DIM + (size_t)lane * 4;
    atomicAdd(op + 0, v * bv.x);
    atomicAdd(op + 1, v * bv.y);
    atomicAdd(op + 2, v * bv.z);
    atomicAdd(op + 3, v * bv.w);
}

extern "C" void kernel_launch(void* const* d_in, const int* in_sizes, int n_in,
                              void* d_out, int out_size, void* d_ws, size_t ws_size,
                              hipStream_t stream) {
    const int*   indices = (const int*)d_in[0];
    const float* vals    = (const float*)d_in[1];
    const float* b       = (const float*)d_in[3];
    float*       out     = (float*)d_out;

    int E = in_sizes[1];
    int N = out_size / D_DIM;
    const int* rows = indices;
    const int* cols = indices + E;

    // ---- workspace layout ----
    size_t nb4  = (size_t)N * sizeof(int);
    size_t need = 3 * nb4 + 1024 + (size_t)E * (sizeof(int) + sizeof(float));
    if (ws_size < need) {
        // fallback: atomic scatter (v1)
        hipMemsetAsync(d_out, 0, (size_t)out_size * sizeof(float), stream);
        long long total = (long long)E * 32;
        int blocks = (int)((total + 255) / 256);
        spmm_atomic_kernel<<<blocks, 256, 0, stream>>>(rows, cols, vals, b, out, E);
        return;
    }
    char* w = (char*)d_ws;
    int*   counts    = (int*)w;                w += nb4;
    int*   offsets   = (int*)w;                w += nb4;
    int*   cursor    = (int*)w;                w += nb4;
    int*   blocksums = (int*)w;                w += 1024;
    int*   csr_col   = (int*)w;                w += (size_t)E * sizeof(int);
    float* csr_val   = (float*)w;

    // 1. zero counts (ws is poisoned 0xAA every call)
    hipMemsetAsync(counts, 0, nb4, stream);

    // 2. histogram
    hist_kernel<<<(E + 255) / 256, 256, 0, stream>>>(rows, counts, E);

    // 3. scan: per-block, then block sums, then add base (+ init cursor)
    int nscan = (N + 1023) / 1024;  // 98 for N=100000
    scan_block_kernel<<<nscan, 256, 0, stream>>>(counts, offsets, blocksums, N);
    scan_sums_kernel<<<1, 256, 0, stream>>>(blocksums, nscan);
    add_base_kernel<<<(N + 255) / 256, 256, 0, stream>>>(offsets, blocksums, cursor, N);

    // 4. scatter edges into CSR order
    scatter_kernel<<<(E + 255) / 256, 256, 0, stream>>>(rows, cols, vals, cursor,
                                                        csr_col, csr_val, E);

    // 5. gather-accumulate, write-once output (no out memset needed: every row written)
    long long total = (long long)N * 32;
    int blocks = (int)((total + 255) / 256);
    gather_kernel<<<blocks, 256, 0, stream>>>(offsets, counts, csr_col, csr_val, b, out, N);
}

// Round 4
// 324.311 us; speedup vs baseline: 8.5225x; 1.2186x over previous
//
#include <hip/hip_runtime.h>

// COO SpMM: out[row[e], :] += values[e] * b[col[e], :]
// N=100000, E=1600000, D=128, fp32.
// v3b: padded-slot bucketing (no hist/scan). Scatter = 1 atomic + 1 packed 8B
//      store per edge. Gather = 8-wide edge preload + shfl broadcast for MLP.
//      Overflow edges (P~0 at S=64) handled by post-gather atomic fixup.

#define D_DIM 128
#define OVF_MAX 65536

typedef float fx4 __attribute__((ext_vector_type(4)));  // native vec for NT store

// ---------------- scatter into padded row buckets ----------------
__global__ void scatter_slots_kernel(const int* __restrict__ rows,
                                     const int* __restrict__ cols,
                                     const float* __restrict__ vals,
                                     int* __restrict__ cursor,
                                     int2* __restrict__ slots,
                                     int* __restrict__ ovf_cnt,
                                     int* __restrict__ ovf_list,
                                     int E, int S) {
    int e = blockIdx.x * blockDim.x + threadIdx.x;
    if (e >= E) return;
    int r = rows[e];
    int pos = atomicAdd(&cursor[r], 1);
    if (pos < S) {
        slots[(size_t)r * S + pos] = make_int2(cols[e], __float_as_int(vals[e]));
    } else {
        int k = atomicAdd(ovf_cnt, 1);
        if (k < OVF_MAX) ovf_list[k] = e;
    }
}

// ---------------- gather-accumulate with 8-wide MLP ----------------
// 32 lanes per row, each lane owns one float4 of the 128-wide row.
__global__ __launch_bounds__(256) void gather_slots_kernel(
        const int* __restrict__ cursor,
        const int2* __restrict__ slots,
        const float* __restrict__ b,
        float* __restrict__ out, int N, int S) {
    int t = blockIdx.x * blockDim.x + threadIdx.x;
    int r = t >> 5;
    if (r >= N) return;
    int lane = t & 31;

    int cnt = cursor[r];
    if (cnt > S) cnt = S;
    const int2* rs = slots + (size_t)r * S;

    float4 acc = make_float4(0.f, 0.f, 0.f, 0.f);
    for (int base = 0; base < cnt; base += 8) {
        // lanes cooperatively load 8 edges (dup x4 across the 32 lanes; 1 line)
        int slot_idx = base + (lane & 7);
        int2 ev = rs[slot_idx];                 // in-bounds: base+7 <= S-1
        bool valid = slot_idx < cnt;
        int   c = valid ? ev.x : 0;             // invalid -> b[0], weight 0
        float v = valid ? __int_as_float(ev.y) : 0.0f;
#pragma unroll
        for (int i = 0; i < 8; ++i) {
            int   ci = __shfl(c, i, 8);
            float vi = __shfl(v, i, 8);
            float4 bv = ((const float4*)(b + (size_t)ci * D_DIM))[lane];
            acc.x += vi * bv.x;
            acc.y += vi * bv.y;
            acc.z += vi * bv.z;
            acc.w += vi * bv.w;
        }
    }
    fx4 accv = {acc.x, acc.y, acc.z, acc.w};
    __builtin_nontemporal_store(accv, (fx4*)(out + (size_t)r * D_DIM) + lane);
}

// ---------------- overflow fixup (normally 0 items) ----------------
__global__ void fixup_kernel(const int* __restrict__ ovf_cnt,
                             const int* __restrict__ ovf_list,
                             const int* __restrict__ rows,
                             const int* __restrict__ cols,
                             const float* __restrict__ vals,
                             const float* __restrict__ b,
                             float* __restrict__ out) {
    int items = *ovf_cnt;
    if (items > OVF_MAX) items = OVF_MAX;
    int gsz  = (gridDim.x * blockDim.x) >> 5;
    int gid  = (blockIdx.x * blockDim.x + threadIdx.x) >> 5;
    int lane = threadIdx.x & 31;
    for (int i = gid; i < items; i += gsz) {
        int e = ovf_list[i];
        int r = rows[e];
        int c = cols[e];
        float v = vals[e];
        float4 bv = ((const float4*)(b + (size_t)c * D_DIM))[lane];
        float* op = out + (size_t)r * D_DIM + (size_t)lane * 4;
        atomicAdd(op + 0, v * bv.x);
        atomicAdd(op + 1, v * bv.y);
        atomicAdd(op + 2, v * bv.z);
        atomicAdd(op + 3, v * bv.w);
    }
}

// ---------------- fallback (v1 atomic) ----------------
__global__ void spmm_atomic_kernel(const int* __restrict__ rows,
                                   const int* __restrict__ cols,
                                   const float* __restrict__ vals,
                                   const float* __restrict__ b,
                                   float* __restrict__ out, int E) {
    int t = blockIdx.x * blockDim.x + threadIdx.x;
    int e = t >> 5;
    if (e >= E) return;
    int lane = t & 31;
    int r = rows[e];
    int c = cols[e];
    float v = vals[e];
    float4 bv = ((const float4*)(b + (size_t)c * D_DIM))[lane];
    float* op = out + (size_t)r * D_DIM + (size_t)lane * 4;
    atomicAdd(op + 0, v * bv.x);
    atomicAdd(op + 1, v * bv.y);
    atomicAdd(op + 2, v * bv.z);
    atomicAdd(op + 3, v * bv.w);
}

extern "C" void kernel_launch(void* const* d_in, const int* in_sizes, int n_in,
                              void* d_out, int out_size, void* d_ws, size_t ws_size,
                              hipStream_t stream) {
    const int*   indices = (const int*)d_in[0];
    const float* vals    = (const float*)d_in[1];
    const float* b       = (const float*)d_in[3];
    float*       out     = (float*)d_out;

    int E = in_sizes[1];
    int N = out_size / D_DIM;
    const int* rows = indices;
    const int* cols = indices + E;

    // ---- workspace layout: cursor[N] | ovf_cnt | ovf_list[OVF_MAX] | slots[N*S]
    size_t fixed     = (size_t)N * 4 + 4 + (size_t)OVF_MAX * 4;
    size_t slots_off = (fixed + 255) & ~(size_t)255;

    int S = 0;
    if (ws_size >= slots_off + (size_t)N * 64 * 8)      S = 64;
    else if (ws_size >= slots_off + (size_t)N * 48 * 8) S = 48;
    else if (ws_size >= slots_off + (size_t)N * 32 * 8) S = 32;

    if (S == 0) {
        // fallback: atomic scatter (v1)
        (void)hipMemsetAsync(d_out, 0, (size_t)out_size * sizeof(float), stream);
        long long total = (long long)E * 32;
        int blocks = (int)((total + 255) / 256);
        spmm_atomic_kernel<<<blocks, 256, 0, stream>>>(rows, cols, vals, b, out, E);
        return;
    }

    char* w = (char*)d_ws;
    int*  cursor   = (int*)w;
    int*  ovf_cnt  = (int*)(w + (size_t)N * 4);
    int*  ovf_list = (int*)(w + (size_t)N * 4 + 4);
    int2* slots    = (int2*)(w + slots_off);

    // zero cursor + ovf_cnt in one memset (ws is re-poisoned each call)
    (void)hipMemsetAsync(cursor, 0, (size_t)N * 4 + 4, stream);

    scatter_slots_kernel<<<(E + 255) / 256, 256, 0, stream>>>(
        rows, cols, vals, cursor, slots, ovf_cnt, ovf_list, E, S);

    long long total = (long long)N * 32;
    int blocks = (int)((total + 255) / 256);
    gather_slots_kernel<<<blocks, 256, 0, stream>>>(cursor, slots, b, out, N, S);

    fixup_kernel<<<8, 256, 0, stream>>>(ovf_cnt, ovf_list, rows, cols, vals, b, out);
}